// Round 14
// baseline (90.090 us; speedup 1.0000x reference)
//
#include <hip/hip_runtime.h>

typedef unsigned long long u64;
typedef unsigned int u32;

#define N1 4096
#define N2 2048
#define NT 6144
#define CAP 4096
#define MCAP 4096
#define MGCAP 2048
#define IMG 1280.0f
#define MATCH_IOU_T 0.8f
#define NMS_IOU_T 0.95f

// IoU with exact op-order mirroring of the reference (no FMA contraction).
__device__ __forceinline__ float iou_f(const float* a, const float* b) {
    float x1 = fmaxf(a[0], b[0]);
    float y1 = fmaxf(a[1], b[1]);
    float x2 = fminf(a[2], b[2]);
    float y2 = fminf(a[3], b[3]);
    float dx = fmaxf(__fsub_rn(x2, x1), 0.0f);
    float dy = fmaxf(__fsub_rn(y2, y1), 0.0f);
    float inter = __fmul_rn(dx, dy);
    float a1 = __fmul_rn(__fsub_rn(a[2], a[0]), __fsub_rn(a[3], a[1]));
    float a2 = __fmul_rn(__fsub_rn(b[2], b[0]), __fsub_rn(b[3], b[1]));
    float den = __fsub_rn(__fadd_rn(a1, a2), inter);
    return __fdiv_rn(inter, den);
}

__device__ __forceinline__ u64 make_key(float f, int idx) {
    u32 u = __float_as_uint(f);
    u32 asc = (u >> 31) ? ~u : (u | 0x80000000u);
    return (((u64)(~asc)) << 32) | (u32)idx;
}

// kX: ONE yolo row per block (wide grid = max latency hiding). Emit all
// candidate pairs (same label, unmasked IoU >= 0.8) with exact IoU; frcnn
// boxes normalized inline (bit-identical to dividing once up front).
__global__ void __launch_bounds__(256) kX(const float* yb, const int* yl,
                                          const int* fl, const float* fb,
                                          int* mpcount, u64* mpk, float* mpi) {
    int i = blockIdx.x;
    int tid = threadIdx.x;
    float a[4];
#pragma unroll
    for (int c = 0; c < 4; c++) a[c] = __fdiv_rn(yb[i * 4 + c], IMG);
    int lab = yl[i];
    for (int j = tid; j < N2; j += 256) {
        if (fl[j] == lab) {
            float bb[4];
#pragma unroll
            for (int c = 0; c < 4; c++) bb[c] = __fdiv_rn(fb[j * 4 + c], IMG);
            float v = iou_f(a, bb);
            if (v >= MATCH_IOU_T) {
                int pos = atomicAdd(mpcount, 1);
                if (pos < MCAP) { mpk[pos] = (((u64)(u32)i) << 32) | (u32)j; mpi[pos] = v; }
            }
        }
    }
}

// kY: 384 blocks x 16 rows. Each block REDUNDANTLY resolves the greedy match
// in LDS (deterministic: sorted pairs + fixed walk => identical result in
// every block; ~2us redundant work, fully parallel), builds the 6144 sort
// keys in LDS (patching merged scores), ranks its 16 rows, and gathers
// directly to output. Removes the 1-block resolve dispatch AND all global
// mbox/mscore/keys round-trips. No fences (r12: device fences ~100us/kernel).
__global__ void __launch_bounds__(256) kY(const float* yb, const float* ys,
                                          const int* yl, const int* fl,
                                          const float* fb, const float* fs,
                                          const int* mpcount, const u64* mpk,
                                          const float* mpi,
                                          float* sboxn, int* slab, int* svalid,
                                          float* out) {
    __shared__ u64 A[NT];                 // 48 KB: pair keys, then sort keys
    __shared__ float pv[MCAP];            // 16 KB
    __shared__ unsigned short mgi[MGCAP]; //  4 KB  merged i (ascending)
    __shared__ unsigned short mgj[MGCAP]; //  4 KB  merged j
    __shared__ float mgt[MGCAP];          //  8 KB  merged total score
    __shared__ unsigned char used[N2];    //  2 KB
    __shared__ int cnt_m_s;
    __shared__ int cnts[16];
    int tid = threadIdx.x;
    int np = *mpcount;
    if (np > MCAP) np = MCAP;
    for (int t = tid; t < MCAP; t += 256) {
        A[t] = (t < np) ? mpk[t] : ~0ULL;
        pv[t] = (t < np) ? mpi[t] : 0.0f;
    }
    for (int j = tid; j < N2; j += 256) used[j] = 0;
    if (tid == 0) cnt_m_s = 0;
    __syncthreads();
    if (np > 0) {
        // bitonic sort (A,pv) by A over pow2(np): restores determinism after
        // atomic append; (i<<32)|j order == argmax lowest-j tie-break.
        int m = 2;
        while (m < np) m <<= 1;
        for (int k2 = 2; k2 <= m; k2 <<= 1) {
            for (int jj = k2 >> 1; jj > 0; jj >>= 1) {
                for (int idx = tid; idx < m; idx += 256) {
                    int l = idx ^ jj;
                    if (l > idx) {
                        u64 Av = A[idx], Bv = A[l];
                        bool up = ((idx & k2) == 0);
                        if (up ? (Av > Bv) : (Av < Bv)) {
                            A[idx] = Bv; A[l] = Av;
                            float fA = pv[idx]; pv[idx] = pv[l]; pv[l] = fA;
                        }
                    }
                }
                __syncthreads();
            }
        }
        // serial greedy walk: per i-group pick strict-max unused iou
        if (tid == 0) {
            int cm = 0;
            int cur_i = -1, best_p = -1, best_j = -1;
            float best_v = -1.0f;
            for (int p = 0; p < np; p++) {
                u64 pr = A[p];
                int i = (int)(pr >> 32);
                int j = (int)(pr & 0xffffffffu);
                if (i != cur_i) {
                    if (best_p >= 0) {
                        mgi[cm] = (unsigned short)cur_i;
                        mgj[cm] = (unsigned short)best_j;
                        cm++; used[best_j] = 1;
                    }
                    cur_i = i; best_p = -1; best_j = -1; best_v = -1.0f;
                }
                if (!used[j]) {
                    float v = pv[p];
                    if (v > best_v) { best_v = v; best_p = p; best_j = j; }
                }
            }
            if (best_p >= 0) {
                mgi[cm] = (unsigned short)cur_i;
                mgj[cm] = (unsigned short)best_j;
                cm++; used[best_j] = 1;
            }
            cnt_m_s = cm;
        }
    }
    __syncthreads();
    int cm = cnt_m_s;
    // merged totals: tot = (ys[i]*0.5) + (fs[j]*0.5) — bit-equal to the old
    // store-then-load path (both fmul results are exact f32 stores).
    for (int t = tid; t < cm; t += 256) {
        int i = mgi[t], j = mgj[t];
        mgt[t] = __fadd_rn(__fmul_rn(ys[i], 0.5f), __fmul_rn(fs[j], 0.5f));
    }
    __syncthreads();   // walk/pv reads done -> safe to overwrite A with keys
    // default keys for all rows
    for (int idx = tid; idx < NT; idx += 256) {
        float sc; int val;
        if (idx < N1) { sc = __fmul_rn(ys[idx], 0.5f); val = 1; }
        else          { sc = __fmul_rn(fs[idx - N1], 0.5f); val = used[idx - N1] ? 0 : 1; }
        A[idx] = make_key(val ? sc : -1.0f, idx);
    }
    __syncthreads();
    // patch merged rows' keys (disjoint writes)
    for (int t = tid; t < cm; t += 256) A[mgi[t]] = make_key(mgt[t], (int)mgi[t]);
    if (tid < 16) cnts[tid] = 0;
    __syncthreads();
    // rank-count 16 rows against LDS keys
    int i0 = blockIdx.x * 16;
    u64 myk[16];
#pragma unroll
    for (int g = 0; g < 16; g++) myk[g] = A[i0 + g];
    int local[16];
#pragma unroll
    for (int g = 0; g < 16; g++) local[g] = 0;
    for (int j = tid; j < NT; j += 256) {
        u64 kj = A[j];
#pragma unroll
        for (int g = 0; g < 16; g++) local[g] += (kj < myk[g]) ? 1 : 0;
    }
#pragma unroll
    for (int g = 0; g < 16; g++) {
        int v = local[g];
#pragma unroll
        for (int s = 32; s > 0; s >>= 1) v += __shfl_down(v, s, 64);
        if ((tid & 63) == 0) atomicAdd(&cnts[g], v);
    }
    __syncthreads();
    // gather: ranks unique -> disjoint scatter writes
    if (tid < 16) {
        int i = i0 + tid;
        int r = cnts[tid];
        float b[4]; int lab; float sc; int val;
        if (i < N1) {
#pragma unroll
            for (int c = 0; c < 4; c++) b[c] = __fdiv_rn(yb[i * 4 + c], IMG);
            lab = yl[i]; sc = __fmul_rn(ys[i], 0.5f); val = 1;
            // binary search merged list (mgi strictly ascending)
            int lo = 0, hi = cm - 1, f = -1;
            while (lo <= hi) {
                int mid = (lo + hi) >> 1;
                int v = mgi[mid];
                if (v == i) { f = mid; break; }
                if (v < i) lo = mid + 1; else hi = mid - 1;
            }
            if (f >= 0) {
                int j = mgj[f]; float tot = mgt[f];
                float sc0 = sc;
                float s2 = __fmul_rn(fs[j], 0.5f);
#pragma unroll
                for (int c = 0; c < 4; c++) {
                    float b2v = __fdiv_rn(fb[j * 4 + c], IMG);
                    b[c] = __fdiv_rn(__fadd_rn(__fmul_rn(b[c], sc0),
                                               __fmul_rn(b2v, s2)), tot);
                }
                sc = tot;
            }
        } else {
            int j = i - N1;
#pragma unroll
            for (int c = 0; c < 4; c++) b[c] = __fdiv_rn(fb[j * 4 + c], IMG);
            lab = fl[j]; sc = __fmul_rn(fs[j], 0.5f); val = used[j] ? 0 : 1;
        }
#pragma unroll
        for (int c = 0; c < 4; c++) {
            sboxn[r * 4 + c] = b[c];
            out[r * 4 + c] = __fmul_rn(b[c], IMG);
        }
        slab[r] = lab; svalid[r] = val;
        out[24576 + r] = (lab == 0) ? 2.0f : 1.0f;   // label_map[clip(l,0,1)]
        out[24576 + NT + r] = sc;                     // sorted scores
    }
}

// kZ: ONE sorted row per block. NMS candidate pairs (i<j, same label,
// IoU >= 0.95) -> atomic append.
__global__ void __launch_bounds__(256) kZ(const float* sboxn, const int* slab,
                                          int* pcount, u64* pairs) {
    int i = blockIdx.x;
    int tid = threadIdx.x;
    float a[4] = {sboxn[i * 4], sboxn[i * 4 + 1], sboxn[i * 4 + 2], sboxn[i * 4 + 3]};
    int lab = slab[i];
    for (int j = i + 1 + tid; j < NT; j += 256) {
        if (slab[j] == lab) {
            float bb[4] = {sboxn[j * 4], sboxn[j * 4 + 1], sboxn[j * 4 + 2], sboxn[j * 4 + 3]};
            if (iou_f(a, bb) >= NMS_IOU_T) {
                int pos = atomicAdd(pcount, 1);
                if (pos < CAP) pairs[pos] = (((u64)(u32)i) << 32) | (u32)j;
            }
        }
    }
}

// kW: single block. Sort pairs (determinism after atomic append), exact
// sequential suppression, keep mask. Runtime-sized bitonic.
__global__ void __launch_bounds__(256) kW(const int* pcount, const u64* pairs,
                                          const int* svalid, float* out) {
    __shared__ u64 pl[CAP];
    __shared__ unsigned char sup[NT];
    int tid = threadIdx.x;
    int np = *pcount;
    if (np > CAP) np = CAP;
    int m = 2;
    while (m < np) m <<= 1;   // block-uniform
    for (int t = tid; t < m; t += 256) pl[t] = (t < np) ? pairs[t] : ~0ULL;
    for (int k = tid; k < NT; k += 256) sup[k] = svalid[k] ? 0 : 1;
    __syncthreads();
    if (np > 0) {
        for (int k2 = 2; k2 <= m; k2 <<= 1) {
            for (int jj = k2 >> 1; jj > 0; jj >>= 1) {
                for (int idx = tid; idx < m; idx += 256) {
                    int l = idx ^ jj;
                    if (l > idx) {
                        u64 A = pl[idx], B = pl[l];
                        bool up = ((idx & k2) == 0);
                        if (up ? (A > B) : (A < B)) { pl[idx] = B; pl[l] = A; }
                    }
                }
                __syncthreads();
            }
        }
        if (tid == 0) {
            for (int p = 0; p < np; p++) {
                u64 pr = pl[p];
                int i = (int)(pr >> 32);
                int j = (int)(pr & 0xffffffffu);
                if (!sup[i]) sup[j] = 1;
            }
        }
        __syncthreads();
    }
    for (int k = tid; k < NT; k += 256) out[24576 + 2 * NT + k] = sup[k] ? 0.0f : 1.0f;
}

extern "C" void kernel_launch(void* const* d_in, const int* in_sizes, int n_in,
                              void* d_out, int out_size, void* d_ws, size_t ws_size,
                              hipStream_t stream) {
    const float* yb = (const float*)d_in[0];
    const float* ys = (const float*)d_in[1];
    const int*   yl = (const int*)d_in[2];
    const float* fb = (const float*)d_in[3];
    const float* fs = (const float*)d_in[4];
    const int*   fl = (const int*)d_in[5];
    float* out = (float*)d_out;
    char* ws = (char*)d_ws;

    float* sboxn   = (float*)(ws);            // 6144*4 f = 98304 B
    int*   slab    = (int*)  (ws + 98304);    // 6144 i   = 24576 B
    int*   svalid  = (int*)  (ws + 122880);   // 6144 i   = 24576 B
    int*   cnt     = (int*)  (ws + 147456);   // 2 ints: pcount, mpcount
    u64*   mpk     = (u64*)  (ws + 147472);   // 4096 u64 = 32768 B
    float* mpi     = (float*)(ws + 180240);   // 4096 f   = 16384 B
    u64*   pairs   = (u64*)  (ws + 196624);   // 4096 u64 = 32768 B (end ~230 KB)
    int* pcount  = cnt + 0;
    int* mpcount = cnt + 1;

    hipMemsetAsync(cnt, 0, 8, stream);
    hipLaunchKernelGGL(kX, dim3(N1),    dim3(256), 0, stream,
                       yb, yl, fl, fb, mpcount, mpk, mpi);
    hipLaunchKernelGGL(kY, dim3(NT/16), dim3(256), 0, stream,
                       yb, ys, yl, fl, fb, fs, mpcount, mpk, mpi,
                       sboxn, slab, svalid, out);
    hipLaunchKernelGGL(kZ, dim3(NT),    dim3(256), 0, stream,
                       sboxn, slab, pcount, pairs);
    hipLaunchKernelGGL(kW, dim3(1),     dim3(256), 0, stream,
                       pcount, pairs, svalid, out);
}